// Round 3
// baseline (2306.951 us; speedup 1.0000x reference)
//
#include <hip/hip_runtime.h>
#include <stdint.h>

#define K_DIM 4096
#define N_DIM 16384
#define M_DIM 8192

typedef __attribute__((ext_vector_type(8))) __bf16 bf16x8;
typedef __attribute__((ext_vector_type(4))) float f32x4;
typedef __attribute__((ext_vector_type(8))) unsigned short us8;

__device__ __forceinline__ void async_ld16(const void* g, void* l) {
    __builtin_amdgcn_global_load_lds((const __attribute__((address_space(1))) void*)g,
                                     (__attribute__((address_space(3))) void*)l, 16, 0, 0);
}

__device__ __forceinline__ unsigned short bf16_rn(float f) {
    unsigned b = __builtin_bit_cast(unsigned, f);
    return (unsigned short)((b + 0x7fffu + ((b >> 16) & 1u)) >> 16);
}

// ---------- pre-pass: int32-boxed int8 weights -> bf16 (exact, |q|<=127) ----------
__global__ __launch_bounds__(256) void qlin_cvt_w(const int* __restrict__ wq,
                                                  unsigned short* __restrict__ w2,
                                                  int total16) {
    int idx = blockIdx.x * 256 + threadIdx.x;
    int stride = gridDim.x * 256;
    for (; idx < total16; idx += stride) {
        const int4* src = reinterpret_cast<const int4*>(wq) + (size_t)idx * 4;
        int4 a = src[0], b = src[1], c = src[2], d = src[3];
        int v[16] = {a.x, a.y, a.z, a.w, b.x, b.y, b.z, b.w,
                     c.x, c.y, c.z, c.w, d.x, d.y, d.z, d.w};
        us8 o0, o1;
#pragma unroll
        for (int e = 0; e < 8; ++e) {
            float f0 = (float)v[e];        // exact in bf16 (<=8 mantissa bits)
            float f1 = (float)v[8 + e];
            o0[e] = (unsigned short)(__builtin_bit_cast(unsigned, f0) >> 16);
            o1[e] = (unsigned short)(__builtin_bit_cast(unsigned, f1) >> 16);
        }
        us8* dst = reinterpret_cast<us8*>(w2 + (size_t)idx * 16);
        dst[0] = o0; dst[1] = o1;
    }
}

// ---------- pre-pass: f32 x -> bf16 (round-nearest-even) ----------
__global__ __launch_bounds__(256) void qlin_cvt_a(const float* __restrict__ x,
                                                  unsigned short* __restrict__ ab,
                                                  int total8) {
    int idx = blockIdx.x * 256 + threadIdx.x;
    int stride = gridDim.x * 256;
    for (; idx < total8; idx += stride) {
        const float4* src = reinterpret_cast<const float4*>(x + (size_t)idx * 8);
        float4 v0 = src[0], v1 = src[1];
        float f[8] = {v0.x, v0.y, v0.z, v0.w, v1.x, v1.y, v1.z, v1.w};
        us8 h;
#pragma unroll
        for (int e = 0; e < 8; ++e) h[e] = bf16_rn(f[e]);
        *reinterpret_cast<us8*>(ab + (size_t)idx * 8) = h;
    }
}

// ---------- tile compute: 16 MFMA per K-step (m97 structure) ----------
__device__ __forceinline__ void tile_mfma(const unsigned short* sA, const unsigned short* sW,
                                          f32x4 (&acc)[4][4], int r, int kc, int wr, int wc) {
    bf16x8 fw[4], fa[4];
#pragma unroll
    for (int ni = 0; ni < 4; ++ni)
        fw[ni] = *reinterpret_cast<const bf16x8*>(&sW[(wc + ni * 16 + r) * 32 + kc * 8]);
#pragma unroll
    for (int mi = 0; mi < 4; ++mi)
        fa[mi] = *reinterpret_cast<const bf16x8*>(&sA[(wr + mi * 16 + r) * 32 + kc * 8]);
#pragma unroll
    for (int mi = 0; mi < 4; ++mi)
#pragma unroll
        for (int ni = 0; ni < 4; ++ni)
            acc[mi][ni] = __builtin_amdgcn_mfma_f32_16x16x32_bf16(fa[mi], fw[ni], acc[mi][ni], 0, 0, 0);
}

__device__ __forceinline__ void epilogue(f32x4 (&acc)[4][4], const float* __restrict__ scale,
                                         const float* __restrict__ bias, float* __restrict__ out,
                                         int bm, int bn, int wr, int wc, int lane) {
    // C/D layout (m89-verified): col = lane&15, row = (lane>>4)*4 + j
    int r = lane & 15, rq = (lane >> 4) * 4;
#pragma unroll
    for (int ni = 0; ni < 4; ++ni) {
        int c = bn + wc + ni * 16 + r;
        float s = scale[c], bb = bias[c];
#pragma unroll
        for (int mi = 0; mi < 4; ++mi) {
            int r0 = bm + wr + mi * 16 + rq;
#pragma unroll
            for (int j = 0; j < 4; ++j)
                out[(size_t)(r0 + j) * N_DIM + c] = acc[mi][ni][j] * s + bb;
        }
    }
}

// ---------- fast path: bf16 GEMM, global_load_lds staging (m97 structure) ----------
__global__ __launch_bounds__(256, 2) void qlin_gemm_fast(const unsigned short* __restrict__ Ab,
                                                         const unsigned short* __restrict__ Wt,
                                                         const float* __restrict__ scale,
                                                         const float* __restrict__ bias,
                                                         float* __restrict__ out) {
    __shared__ unsigned short sA[128 * 32], sW[128 * 32];
    const int tid = threadIdx.x;
    const int lane = tid & 63;
    const int wid = tid >> 6;
    // XCD-aware bijective swizzle (nwg = 8192, %8 == 0)
    int id2 = ((int)blockIdx.x & 7) * 1024 + ((int)blockIdx.x >> 3);
    const int bm = (id2 >> 7) * 128;   // 64 M-tiles
    const int bn = (id2 & 127) * 128;  // 128 N-tiles
    const int wr = (wid >> 1) * 64;
    const int wc = (wid & 1) * 64;

    // staging: 16 KB/step = 16 chunks of 1 KB; wave w owns chunks w*4..w*4+3
    const unsigned short* gsrc[4];
    unsigned short* ldst[4];
#pragma unroll
    for (int i = 0; i < 4; ++i) {
        int chunk = wid * 4 + i;
        int tile = chunk >> 3, c8 = chunk & 7;
        const unsigned short* src = (tile == 0) ? Ab : Wt;
        unsigned short* dst = (tile == 0) ? sA : sW;
        int rb = (tile == 0) ? bm : bn;
        int row = c8 * 16 + (lane >> 2);
        gsrc[i] = src + (size_t)(rb + row) * K_DIM + (lane & 3) * 8; // per-lane global addr
        ldst[i] = dst + c8 * 512;                                    // wave-uniform LDS base
    }

    f32x4 acc[4][4] = {};
    const int r = lane & 15, kc = lane >> 4;

    for (int kt = 0; kt < K_DIM / 32; ++kt) {
        __syncthreads();  // all waves done reading previous tile
#pragma unroll
        for (int i = 0; i < 4; ++i) async_ld16(gsrc[i] + (size_t)kt * 32, ldst[i]);
        __syncthreads();  // barrier drains vmcnt -> tile visible
        tile_mfma(sA, sW, acc, r, kc, wr, wc);
    }
    epilogue(acc, scale, bias, out, bm, bn, wr, wc, lane);
}

// ---------- fallback: reg-staged, on-the-fly conversion (no workspace) ----------
__global__ __launch_bounds__(256, 2) void qlin_gemm_fb(const float* __restrict__ x,
                                                       const int* __restrict__ wq,
                                                       const float* __restrict__ scale,
                                                       const float* __restrict__ bias,
                                                       float* __restrict__ out) {
    __shared__ unsigned short sA[128 * 32], sW[128 * 32];
    const int tid = threadIdx.x;
    const int lane = tid & 63;
    const int wid = tid >> 6;
    int id2 = ((int)blockIdx.x & 7) * 1024 + ((int)blockIdx.x >> 3);
    const int bm = (id2 >> 7) * 128;
    const int bn = (id2 & 127) * 128;
    const int wr = (wid >> 1) * 64;
    const int wc = (wid & 1) * 64;

    const int row = tid >> 1, half = tid & 1;          // 16 elems per thread per tile
    const float* ga = x  + (size_t)(bm + row) * K_DIM + half * 16;
    const int*   gw = wq + (size_t)(bn + row) * K_DIM + half * 16;
    us8* dA = reinterpret_cast<us8*>(&sA[row * 32 + half * 16]);
    us8* dW = reinterpret_cast<us8*>(&sW[row * 32 + half * 16]);

    f32x4 acc[4][4] = {};
    const int r = lane & 15, kc = lane >> 4;

    for (int kt = 0; kt < K_DIM / 32; ++kt) {
        const float4* af = reinterpret_cast<const float4*>(ga + kt * 32);
        float4 v0 = af[0], v1 = af[1], v2 = af[2], v3 = af[3];
        const int4* wf = reinterpret_cast<const int4*>(gw + kt * 32);
        int4 w0 = wf[0], w1 = wf[1], w2 = wf[2], w3 = wf[3];
        float f[16] = {v0.x, v0.y, v0.z, v0.w, v1.x, v1.y, v1.z, v1.w,
                       v2.x, v2.y, v2.z, v2.w, v3.x, v3.y, v3.z, v3.w};
        int   q[16] = {w0.x, w0.y, w0.z, w0.w, w1.x, w1.y, w1.z, w1.w,
                       w2.x, w2.y, w2.z, w2.w, w3.x, w3.y, w3.z, w3.w};
        us8 ha[2], hw[2];
#pragma unroll
        for (int e = 0; e < 16; ++e) {
            ha[e >> 3][e & 7] = bf16_rn(f[e]);
            float wv = (float)q[e];
            hw[e >> 3][e & 7] = (unsigned short)(__builtin_bit_cast(unsigned, wv) >> 16);
        }
        __syncthreads();  // previous tile fully consumed
        dA[0] = ha[0]; dA[1] = ha[1];
        dW[0] = hw[0]; dW[1] = hw[1];
        __syncthreads();  // writes visible
        tile_mfma(sA, sW, acc, r, kc, wr, wc);
    }
    epilogue(acc, scale, bias, out, bm, bn, wr, wc, lane);
}

extern "C" void kernel_launch(void* const* d_in, const int* in_sizes, int n_in,
                              void* d_out, int out_size, void* d_ws, size_t ws_size,
                              hipStream_t stream) {
    const float* x  = (const float*)d_in[0];
    const int*   wq = (const int*)d_in[1];   // int8 weights boxed as int32 by harness
    const float* sw = (const float*)d_in[2];
    const float* bs = (const float*)d_in[3];
    float* out = (float*)d_out;

    const size_t need = (size_t)M_DIM * K_DIM * 2   // A bf16 (64 MiB)
                      + (size_t)N_DIM * K_DIM * 2;  // W bf16 (128 MiB)

    if (ws_size >= need) {
        unsigned short* ab = (unsigned short*)d_ws;
        unsigned short* w2 = ab + (size_t)M_DIM * K_DIM;
        qlin_cvt_a<<<2048, 256, 0, stream>>>(x, ab, (M_DIM * (K_DIM / 8)));
        qlin_cvt_w<<<2048, 256, 0, stream>>>(wq, w2, (N_DIM * (K_DIM / 16)));
        qlin_gemm_fast<<<dim3(8192), dim3(256), 0, stream>>>(ab, w2, sw, bs, out);
    } else {
        qlin_gemm_fb<<<dim3(8192), dim3(256), 0, stream>>>(x, wq, sw, bs, out);
    }
}

// Round 4
// 2196.440 us; speedup vs baseline: 1.0503x; 1.0503x over previous
//
#include <hip/hip_runtime.h>
#include <stdint.h>

#define K_DIM 4096
#define N_DIM 16384
#define M_DIM 8192

typedef __attribute__((ext_vector_type(8))) __bf16 bf16x8;
typedef __attribute__((ext_vector_type(4))) float f32x4;
typedef __attribute__((ext_vector_type(8))) unsigned short us8;

__device__ __forceinline__ void async_ld16(const void* g, void* l) {
    __builtin_amdgcn_global_load_lds((const __attribute__((address_space(1))) void*)g,
                                     (__attribute__((address_space(3))) void*)l, 16, 0, 0);
}

__device__ __forceinline__ unsigned short bf16_rn(float f) {
    unsigned b = __builtin_bit_cast(unsigned, f);
    return (unsigned short)((b + 0x7fffu + ((b >> 16) & 1u)) >> 16);
}

// ---------- pre-pass: int32-boxed int8 weights -> bf16 (exact, |q|<=127) ----------
__global__ __launch_bounds__(256) void qlin_cvt_w(const int* __restrict__ wq,
                                                  unsigned short* __restrict__ w2,
                                                  int total16) {
    int idx = blockIdx.x * 256 + threadIdx.x;
    int stride = gridDim.x * 256;
    for (; idx < total16; idx += stride) {
        const int4* src = reinterpret_cast<const int4*>(wq) + (size_t)idx * 4;
        int4 a = src[0], b = src[1], c = src[2], d = src[3];
        int v[16] = {a.x, a.y, a.z, a.w, b.x, b.y, b.z, b.w,
                     c.x, c.y, c.z, c.w, d.x, d.y, d.z, d.w};
        us8 o0, o1;
#pragma unroll
        for (int e = 0; e < 8; ++e) {
            float f0 = (float)v[e];        // exact in bf16 (<=8 mantissa bits)
            float f1 = (float)v[8 + e];
            o0[e] = (unsigned short)(__builtin_bit_cast(unsigned, f0) >> 16);
            o1[e] = (unsigned short)(__builtin_bit_cast(unsigned, f1) >> 16);
        }
        us8* dst = reinterpret_cast<us8*>(w2 + (size_t)idx * 16);
        dst[0] = o0; dst[1] = o1;
    }
}

// ---------- pre-pass: f32 x -> bf16 (round-nearest-even) ----------
__global__ __launch_bounds__(256) void qlin_cvt_a(const float* __restrict__ x,
                                                  unsigned short* __restrict__ ab,
                                                  int total8) {
    int idx = blockIdx.x * 256 + threadIdx.x;
    int stride = gridDim.x * 256;
    for (; idx < total8; idx += stride) {
        const float4* src = reinterpret_cast<const float4*>(x + (size_t)idx * 8);
        float4 v0 = src[0], v1 = src[1];
        float f[8] = {v0.x, v0.y, v0.z, v0.w, v1.x, v1.y, v1.z, v1.w};
        us8 h;
#pragma unroll
        for (int e = 0; e < 8; ++e) h[e] = bf16_rn(f[e]);
        *reinterpret_cast<us8*>(ab + (size_t)idx * 8) = h;
    }
}

// ---------- tile compute: 16 MFMA per K-step; kx carries the bank-deswizzle XOR ----------
__device__ __forceinline__ void tile_mfma(const unsigned short* sA, const unsigned short* sW,
                                          f32x4 (&acc)[4][4], int r, int kx, int wr, int wc) {
    bf16x8 fw[4], fa[4];
#pragma unroll
    for (int ni = 0; ni < 4; ++ni)
        fw[ni] = *reinterpret_cast<const bf16x8*>(&sW[(wc + ni * 16 + r) * 32 + kx]);
#pragma unroll
    for (int mi = 0; mi < 4; ++mi)
        fa[mi] = *reinterpret_cast<const bf16x8*>(&sA[(wr + mi * 16 + r) * 32 + kx]);
#pragma unroll
    for (int mi = 0; mi < 4; ++mi)
#pragma unroll
        for (int ni = 0; ni < 4; ++ni)
            acc[mi][ni] = __builtin_amdgcn_mfma_f32_16x16x32_bf16(fa[mi], fw[ni], acc[mi][ni], 0, 0, 0);
}

__device__ __forceinline__ void epilogue(f32x4 (&acc)[4][4], const float* __restrict__ scale,
                                         const float* __restrict__ bias, float* __restrict__ out,
                                         int bm, int bn, int wr, int wc, int lane) {
    // C/D layout (m89-verified): col = lane&15, row = (lane>>4)*4 + j
    int r = lane & 15, rq = (lane >> 4) * 4;
#pragma unroll
    for (int ni = 0; ni < 4; ++ni) {
        int c = bn + wc + ni * 16 + r;
        float s = scale[c], bb = bias[c];
#pragma unroll
        for (int mi = 0; mi < 4; ++mi) {
            int r0 = bm + wr + mi * 16 + rq;
#pragma unroll
            for (int j = 0; j < 4; ++j)
                out[(size_t)(r0 + j) * N_DIM + c] = acc[mi][ni][j] * s + bb;
        }
    }
}

// ---------- fast path: bf16 GEMM, global_load_lds staging (m97 structure)
//   + column-strip XCD remap (W panels L2-hot, A panel L3-hot)
//   + source/read XOR swizzle (bank-conflict-free ds_read_b128) ----------
__global__ __launch_bounds__(256, 4) void qlin_gemm_fast(const unsigned short* __restrict__ Ab,
                                                         const unsigned short* __restrict__ Wt,
                                                         const float* __restrict__ scale,
                                                         const float* __restrict__ bias,
                                                         float* __restrict__ out) {
    __shared__ unsigned short sA[128 * 32], sW[128 * 32];
    const int tid = threadIdx.x;
    const int lane = tid & 63;
    const int wid = tid >> 6;
    // Column-strip XCD map: XCD k owns N-tiles [k*16, k*16+16), sweeps M column-major.
    // Resident W working set per XCD ~2 MB (fits 4 MB L2); A (64 MB) stays L3-resident.
    const int xcd = (int)blockIdx.x & 7;
    const int j   = (int)blockIdx.x >> 3;           // 0..1023
    const int bn  = (xcd * 16 + (j >> 6)) * 128;    // 16 N-tiles per XCD strip
    const int bm  = (j & 63) * 128;                 // 64 M-tiles, column-major sweep
    const int wr = (wid >> 1) * 64;
    const int wc = (wid & 1) * 64;

    // staging: 16 KB/step = 16 chunks of 1 KB; wave w owns chunks w*4..w*4+3.
    // Source chunk-in-row pre-swizzled by ((lane>>3)&3) so linear LDS dest holds
    // swizzled data; reads undo it via kx (rule #21: both-sides-or-neither).
    const unsigned short* gsrc[4];
    unsigned short* ldst[4];
#pragma unroll
    for (int i = 0; i < 4; ++i) {
        int chunk = wid * 4 + i;
        int tile = chunk >> 3, c8 = chunk & 7;
        const unsigned short* src = (tile == 0) ? Ab : Wt;
        unsigned short* dst = (tile == 0) ? sA : sW;
        int rb = (tile == 0) ? bm : bn;
        int row = c8 * 16 + (lane >> 2);
        int ci  = (lane & 3) ^ ((lane >> 3) & 3);    // swizzled 16B-chunk within the 64B row
        gsrc[i] = src + (size_t)(rb + row) * K_DIM + ci * 8; // per-lane global addr
        ldst[i] = dst + c8 * 512;                            // wave-uniform linear LDS base
    }

    f32x4 acc[4][4] = {};
    const int r = lane & 15;
    const int kc = lane >> 4;
    const int kx = (kc ^ ((r >> 1) & 3)) * 8;        // de-swizzling read offset (per-lane const)

    for (int kt = 0; kt < K_DIM / 32; ++kt) {
        __syncthreads();  // all waves done reading previous tile
#pragma unroll
        for (int i = 0; i < 4; ++i) async_ld16(gsrc[i] + (size_t)kt * 32, ldst[i]);
        __syncthreads();  // barrier drains vmcnt -> tile visible
        tile_mfma(sA, sW, acc, r, kx, wr, wc);
    }
    epilogue(acc, scale, bias, out, bm, bn, wr, wc, lane);
}

// ---------- fallback: reg-staged, on-the-fly conversion (no workspace) ----------
__global__ __launch_bounds__(256, 2) void qlin_gemm_fb(const float* __restrict__ x,
                                                       const int* __restrict__ wq,
                                                       const float* __restrict__ scale,
                                                       const float* __restrict__ bias,
                                                       float* __restrict__ out) {
    __shared__ unsigned short sA[128 * 32], sW[128 * 32];
    const int tid = threadIdx.x;
    const int lane = tid & 63;
    const int wid = tid >> 6;
    const int xcd = (int)blockIdx.x & 7;
    const int j   = (int)blockIdx.x >> 3;
    const int bn  = (xcd * 16 + (j >> 6)) * 128;
    const int bm  = (j & 63) * 128;
    const int wr = (wid >> 1) * 64;
    const int wc = (wid & 1) * 64;

    const int row = tid >> 1, half = tid & 1;          // 16 elems per thread per tile
    const float* ga = x  + (size_t)(bm + row) * K_DIM + half * 16;
    const int*   gw = wq + (size_t)(bn + row) * K_DIM + half * 16;
    const int x2 = (row >> 1) & 3;                     // write-side swizzle to match kx reads
    us8* bA = reinterpret_cast<us8*>(&sA[row * 32]);
    us8* bW = reinterpret_cast<us8*>(&sW[row * 32]);

    f32x4 acc[4][4] = {};
    const int r = lane & 15;
    const int kc = lane >> 4;
    const int kx = (kc ^ ((r >> 1) & 3)) * 8;

    for (int kt = 0; kt < K_DIM / 32; ++kt) {
        const float4* af = reinterpret_cast<const float4*>(ga + kt * 32);
        float4 v0 = af[0], v1 = af[1], v2 = af[2], v3 = af[3];
        const int4* wf = reinterpret_cast<const int4*>(gw + kt * 32);
        int4 w0 = wf[0], w1 = wf[1], w2 = wf[2], w3 = wf[3];
        float f[16] = {v0.x, v0.y, v0.z, v0.w, v1.x, v1.y, v1.z, v1.w,
                       v2.x, v2.y, v2.z, v2.w, v3.x, v3.y, v3.z, v3.w};
        int   q[16] = {w0.x, w0.y, w0.z, w0.w, w1.x, w1.y, w1.z, w1.w,
                       w2.x, w2.y, w2.z, w2.w, w3.x, w3.y, w3.z, w3.w};
        us8 ha[2], hw[2];
#pragma unroll
        for (int e = 0; e < 16; ++e) {
            ha[e >> 3][e & 7] = bf16_rn(f[e]);
            float wv = (float)q[e];
            hw[e >> 3][e & 7] = (unsigned short)(__builtin_bit_cast(unsigned, wv) >> 16);
        }
        __syncthreads();  // previous tile fully consumed
        bA[(half * 2 + 0) ^ x2] = ha[0];
        bA[(half * 2 + 1) ^ x2] = ha[1];
        bW[(half * 2 + 0) ^ x2] = hw[0];
        bW[(half * 2 + 1) ^ x2] = hw[1];
        __syncthreads();  // writes visible
        tile_mfma(sA, sW, acc, r, kx, wr, wc);
    }
    epilogue(acc, scale, bias, out, bm, bn, wr, wc, lane);
}

extern "C" void kernel_launch(void* const* d_in, const int* in_sizes, int n_in,
                              void* d_out, int out_size, void* d_ws, size_t ws_size,
                              hipStream_t stream) {
    const float* x  = (const float*)d_in[0];
    const int*   wq = (const int*)d_in[1];   // int8 weights boxed as int32 by harness
    const float* sw = (const float*)d_in[2];
    const float* bs = (const float*)d_in[3];
    float* out = (float*)d_out;

    const size_t need = (size_t)M_DIM * K_DIM * 2   // A bf16 (64 MiB)
                      + (size_t)N_DIM * K_DIM * 2;  // W bf16 (128 MiB)

    if (ws_size >= need) {
        unsigned short* ab = (unsigned short*)d_ws;
        unsigned short* w2 = ab + (size_t)M_DIM * K_DIM;
        qlin_cvt_a<<<2048, 256, 0, stream>>>(x, ab, (M_DIM * (K_DIM / 8)));
        qlin_cvt_w<<<2048, 256, 0, stream>>>(wq, w2, (N_DIM * (K_DIM / 16)));
        qlin_gemm_fast<<<dim3(8192), dim3(256), 0, stream>>>(ab, w2, sw, bs, out);
    } else {
        qlin_gemm_fb<<<dim3(8192), dim3(256), 0, stream>>>(x, wq, sw, bs, out);
    }
}